// Round 2
// baseline (443.066 us; speedup 1.0000x reference)
//
#include <hip/hip_runtime.h>
#include <math.h>

typedef unsigned short u16;
typedef __attribute__((ext_vector_type(8))) _Float16 half8;    // 8 fp16
typedef __attribute__((ext_vector_type(4))) float    f32x4;

#define BATCH 4
#define NPB   4096      // pixels per batch (H*W)
#define BN    16384     // BATCH * NPB
#define CC    256       // input channels
#define D     128       // output channels (C/2)
#define LOG2E 1.44269504088896f
#define THR   8.0f      // deferred-rescale threshold (exp2 domain; P <= 256 in fp16)

#if __has_builtin(__builtin_amdgcn_exp2f)
#define EXP2(x) __builtin_amdgcn_exp2f(x)
#else
#define EXP2(x) exp2f(x)
#endif

// 16-lane (DPP row) reductions on the VALU pipe — no LDS crossbar.
template<int CTRL>
__device__ __forceinline__ float dpp_mov(float x) {
    return __builtin_bit_cast(float, __builtin_amdgcn_update_dpp(
        __builtin_bit_cast(int, x), __builtin_bit_cast(int, x),
        CTRL, 0xf, 0xf, false));
}
__device__ __forceinline__ float dpp_row_max(float x) {
    x = fmaxf(x, dpp_mov<0x128>(x));   // row_ror:8
    x = fmaxf(x, dpp_mov<0x124>(x));   // row_ror:4
    x = fmaxf(x, dpp_mov<0x122>(x));   // row_ror:2
    x = fmaxf(x, dpp_mov<0x121>(x));   // row_ror:1
    return x;
}
__device__ __forceinline__ float dpp_row_sum(float x) {
    x += dpp_mov<0x128>(x);
    x += dpp_mov<0x124>(x);
    x += dpp_mov<0x122>(x);
    x += dpp_mov<0x121>(x);
    return x;
}

// ---------------------------------------------------------------------------
// Prep: W[mat] (f32 [256][128]) -> Wt[mat][c][k] fp16 (c-major, contiguous k).
// mat 0 (K) pre-scaled by log2e. 128 blocks x 256 threads x 4 elements.
// ---------------------------------------------------------------------------
__global__ __launch_bounds__(256) void prep_kernel(
    const float* __restrict__ Wk, const float* __restrict__ Wq,
    const float* __restrict__ Wv, const float* __restrict__ Ws,
    u16* __restrict__ Wt)
{
    const int f   = (blockIdx.x * 256 + threadIdx.x) * 4;   // flat output idx
    const int mat = f >> 15;
    const int rem = f & 32767;
    const int c   = rem >> 8;
    const int k0  = rem & 255;
    const float* W = (mat == 0) ? Wk : (mat == 1) ? Wq : (mat == 2) ? Wv : Ws;
    const float scale = (mat == 0) ? LOG2E : 1.0f;
    _Float16 t4[4];
#pragma unroll
    for (int i = 0; i < 4; ++i)
        t4[i] = (_Float16)(W[(size_t)(k0 + i) * D + c] * scale);
    *(uint2*)&Wt[(size_t)mat * 32768 + (size_t)c * 256 + k0] = *(const uint2*)t4;
}

// ---------------------------------------------------------------------------
// Projection: grid (128, 4) = 128-pixel x-tile x one matrix per block.
// (unchanged — isolated this round; becomes the target if it shows > attn)
// ---------------------------------------------------------------------------
#define APJ 264         // As row pitch in u16 (528 B: 16B-aligned, 4-bank row shift)

__global__ __launch_bounds__(256, 2) void proj_kernel(
    const float* __restrict__ x, const u16* __restrict__ Wt,
    const float* __restrict__ bk, const float* __restrict__ bq,
    const float* __restrict__ bv, const float* __restrict__ bs,
    u16* __restrict__ Kh, u16* __restrict__ Qh,
    u16* __restrict__ Vt, float* __restrict__ Sc)
{
    __shared__ __align__(16) u16 As[128][APJ];   // 66 KB -> 2 blocks/CU

    const int tid = threadIdx.x;
    const int wv  = tid >> 6;
    const int l   = tid & 63;
    const int l15 = l & 15;
    const int l4  = l >> 4;
    const int by  = blockIdx.y;
    const int gm0 = blockIdx.x * 128;
    const int c0  = wv * 32;

    // ---- W fragments from Wt: wf[ct][kc], lane -> W[k=kc*32+l4*8..+8][c0+ct*16+l15]
    const u16* wb = Wt + (size_t)by * 32768 + (size_t)(c0 + l15) * 256 + l4 * 8;
    half8 wf[2][8];
#pragma unroll
    for (int ct = 0; ct < 2; ++ct)
#pragma unroll
        for (int kc = 0; kc < 8; ++kc)
            wf[ct][kc] = *(const half8*)(wb + ct * 16 * 256 + kc * 32);

    // ---- stage the 128x256 x-tile once (coalesced: thread t -> float4 i*256+t)
    {
        const float4* xg = (const float4*)(x + (size_t)gm0 * CC);
#pragma unroll 8
        for (int i = 0; i < 32; ++i) {
            const int f = i * 256 + tid;           // flat float4 index
            const float4 v = xg[f];
            const int row = f >> 6, col4 = f & 63;
            _Float16 h[4] = {(_Float16)v.x, (_Float16)v.y,
                             (_Float16)v.z, (_Float16)v.w};
            *(uint2*)&As[row][col4 * 4] = *(const uint2*)h;
        }
    }
    __syncthreads();

    f32x4 acc[8][2];
#pragma unroll
    for (int mt = 0; mt < 8; ++mt) {
        acc[mt][0] = (f32x4){0.f, 0.f, 0.f, 0.f};
        acc[mt][1] = (f32x4){0.f, 0.f, 0.f, 0.f};
    }

    if (by == 2) {
        for (int kc = 0; kc < 8; ++kc)
#pragma unroll
            for (int mt = 0; mt < 8; ++mt) {
                const half8 a = *(const half8*)&As[mt * 16 + l15][kc * 32 + l4 * 8];
                acc[mt][0] = __builtin_amdgcn_mfma_f32_16x16x32_f16(a, wf[0][kc], acc[mt][0], 0, 0, 0);
                acc[mt][1] = __builtin_amdgcn_mfma_f32_16x16x32_f16(a, wf[1][kc], acc[mt][1], 0, 0, 0);
            }
        // V: D[m][c]; fp16 transposed [batch][c][m], pack 4 consecutive m
        const float bb[2] = {bv[c0 + l15], bv[c0 + 16 + l15]};
        const int batch = gm0 >> 12;
        const int mb0   = (gm0 & 4095) + l4 * 4;
        u16* vbp = Vt + (size_t)batch * (D * NPB);
#pragma unroll
        for (int mt = 0; mt < 8; ++mt)
#pragma unroll
            for (int ct = 0; ct < 2; ++ct) {
                const int c = c0 + ct * 16 + l15;
                _Float16 t4[4];
#pragma unroll
                for (int r = 0; r < 4; ++r)
                    t4[r] = (_Float16)(acc[mt][ct][r] + bb[ct]);
                *(uint2*)&vbp[(size_t)c * NPB + mb0 + mt * 16] = *(const uint2*)t4;
            }
    } else {
        for (int kc = 0; kc < 8; ++kc)
#pragma unroll
            for (int mt = 0; mt < 8; ++mt) {
                const half8 a = *(const half8*)&As[mt * 16 + l15][kc * 32 + l4 * 8];
                acc[mt][0] = __builtin_amdgcn_mfma_f32_16x16x32_f16(wf[0][kc], a, acc[mt][0], 0, 0, 0);
                acc[mt][1] = __builtin_amdgcn_mfma_f32_16x16x32_f16(wf[1][kc], a, acc[mt][1], 0, 0, 0);
            }
        // swapped: D[c][m] — lane holds c = c0+ct*16+l4*4+r, m = gm0+mt*16+l15
        if (by == 3) {
            float bb2[2][4];
#pragma unroll
            for (int ct = 0; ct < 2; ++ct)
#pragma unroll
                for (int r = 0; r < 4; ++r)
                    bb2[ct][r] = bs[c0 + ct * 16 + l4 * 4 + r];
#pragma unroll
            for (int mt = 0; mt < 8; ++mt) {
                const int m = gm0 + mt * 16 + l15;
#pragma unroll
                for (int ct = 0; ct < 2; ++ct) {
                    float4 v;
                    v.x = acc[mt][ct][0] + bb2[ct][0];
                    v.y = acc[mt][ct][1] + bb2[ct][1];
                    v.z = acc[mt][ct][2] + bb2[ct][2];
                    v.w = acc[mt][ct][3] + bb2[ct][3];
                    *(float4*)&Sc[(size_t)m * D + c0 + ct * 16 + l4 * 4] = v;
                }
            }
        } else {
            const float* bsrc = (by == 0) ? bk : bq;
            const float scale = (by == 0) ? LOG2E : 1.0f;   // Wt already scaled
            u16* O = (by == 0) ? Kh : Qh;
            float bb2[2][4];
#pragma unroll
            for (int ct = 0; ct < 2; ++ct)
#pragma unroll
                for (int r = 0; r < 4; ++r)
                    bb2[ct][r] = bsrc[c0 + ct * 16 + l4 * 4 + r] * scale;
#pragma unroll
            for (int mt = 0; mt < 8; ++mt) {
                const int m = gm0 + mt * 16 + l15;
#pragma unroll
                for (int ct = 0; ct < 2; ++ct) {
                    _Float16 t4[4];
#pragma unroll
                    for (int r = 0; r < 4; ++r)
                        t4[r] = (_Float16)(acc[mt][ct][r] + bb2[ct][r]);
                    *(uint2*)&O[(size_t)m * D + c0 + ct * 16 + l4 * 4] =
                        *(const uint2*)t4;
                }
            }
        }
    }
}

// ---------------------------------------------------------------------------
// Flash attention v3: barrier-free main loop, global->register fragments,
// 8 waves/block (512 thr) for 4 waves/SIMD latency hiding.
// 512 blocks x 32 n-rows; 8 waves = 8 disjoint 512-m eighths (16 iters x 32 m).
// K/Q/V fragments straight from global (L2-resident via XCD-affinity swizzle).
// Unconditional wrap-around prefetch (branch-free). LDS only for wave-private
// P transpose + one-time 8-way merge (aliased). Deferred rescale (THR=8).
// ---------------------------------------------------------------------------
#define VP  40          // Ps row pitch (u16)
#define OBP 132         // Obuf row pitch (f32): 528 B, 16B-aligned, bank shift 4

__global__ __launch_bounds__(512, 4) void attn_kernel(
    const u16* __restrict__ Kh, const u16* __restrict__ Qh,
    const u16* __restrict__ Vt, const float* __restrict__ Sc,
    float* __restrict__ out)
{
    __shared__ __align__(16) unsigned char smem[4 * 32 * OBP * 4 + 2048]; // 69.6 KB
    u16   (*Ps)[32][VP]    = (u16(*)[32][VP])(smem);              // 20.5 KB, aliases Obuf
    float (*Obuf)[32][OBP] = (float(*)[32][OBP])(smem);           // 67.6 KB
    float (*ml)[2][32]     = (float(*)[2][32])(smem + 4 * 32 * OBP * 4); // [8][2][32]

    const int tid = threadIdx.x;
    const int wv  = tid >> 6;          // 0..7
    const int l   = tid & 63;
    const int l15 = l & 15;
    const int l4  = l >> 4;

    // XCD-affinity remap: round-robin dispatch puts bx%8 on XCD bx%8 ->
    // each XCD pair serves one batch (K+Q+V ~3 MB fits the 4 MB per-XCD L2).
    const int bx    = blockIdx.x;
    const int xcd   = bx & 7;
    const int batch = xcd >> 1;
    const int tile  = ((xcd & 1) << 6) | (bx >> 3);
    const int gr0   = batch * NPB + tile * 32;      // this block's 32 K-rows

    // ---- K fragments straight from global (log2e pre-scaled), held all loop
    half8 kf[2][4];
    {
        const u16* kb = Kh + (size_t)(gr0 + l15) * D + l4 * 8;
#pragma unroll
        for (int nt = 0; nt < 2; ++nt)
#pragma unroll
            for (int kc = 0; kc < 4; ++kc)
                kf[nt][kc] = *(const half8*)(kb + (size_t)nt * 16 * D + kc * 32);
    }

    // ---- per-wave 512-m eighth
    const u16* qbase = Qh + (size_t)(batch * NPB + wv * 512 + l15) * D + l4 * 8;
    const u16* vbase = Vt + (size_t)batch * NPB * D + (size_t)l15 * NPB
                       + wv * 512 + l4 * 8;

    // ---- prologue fragment loads (it = 0)
    half8 qf[2][4], vf[8];
#pragma unroll
    for (int mt = 0; mt < 2; ++mt)
#pragma unroll
        for (int kc = 0; kc < 4; ++kc)
            qf[mt][kc] = *(const half8*)(qbase + (size_t)mt * 16 * D + kc * 32);
#pragma unroll
    for (int ct = 0; ct < 8; ++ct)
        vf[ct] = *(const half8*)(vbase + (size_t)ct * 16 * NPB);

    f32x4 Oc[2][8];
#pragma unroll
    for (int nt = 0; nt < 2; ++nt)
#pragma unroll
        for (int ct = 0; ct < 8; ++ct)
            Oc[nt][ct] = (f32x4){0.f, 0.f, 0.f, 0.f};
    float mold[2][4], lsum[2][4];
#pragma unroll
    for (int nt = 0; nt < 2; ++nt)
#pragma unroll
        for (int r = 0; r < 4; ++r) { mold[nt][r] = -1e30f; lsum[nt][r] = 0.f; }

    for (int it = 0; it < 16; ++it) {
        const int moff = ((it + 1) & 15) * 32;     // wrap: last-iter prefetch reloads tile 0

        // ---- S' = (K*log2e) @ Q^T : 32n x 32m, exp2 domain
        f32x4 sacc[2][2];
        sacc[0][0] = (f32x4){0.f, 0.f, 0.f, 0.f};
        sacc[0][1] = (f32x4){0.f, 0.f, 0.f, 0.f};
        sacc[1][0] = (f32x4){0.f, 0.f, 0.f, 0.f};
        sacc[1][1] = (f32x4){0.f, 0.f, 0.f, 0.f};
        __builtin_amdgcn_s_setprio(1);
#pragma unroll
        for (int kc = 0; kc < 4; ++kc)
#pragma unroll
            for (int nt = 0; nt < 2; ++nt)
#pragma unroll
                for (int mt = 0; mt < 2; ++mt)
                    sacc[nt][mt] = __builtin_amdgcn_mfma_f32_16x16x32_f16(
                        kf[nt][kc], qf[mt][kc], sacc[nt][mt], 0, 0, 0);
        __builtin_amdgcn_s_setprio(0);

        // ---- issue next Q tile now (branch-free; hides under softmax + PV)
        {
            const u16* qn = qbase + (size_t)moff * D;
#pragma unroll
            for (int mt = 0; mt < 2; ++mt)
#pragma unroll
                for (int kc = 0; kc < 4; ++kc)
                    qf[mt][kc] = *(const half8*)(qn + (size_t)mt * 16 * D + kc * 32);
        }

        // ---- online softmax with deferred rescale (T13)
        float rmax[2][4];
        int grow = 0;
#pragma unroll
        for (int nt = 0; nt < 2; ++nt)
#pragma unroll
            for (int r = 0; r < 4; ++r) {
                rmax[nt][r] = dpp_row_max(fmaxf(sacc[nt][0][r], sacc[nt][1][r]));
                grow |= (rmax[nt][r] > mold[nt][r] + THR) ? 1 : 0;
            }
        if (__any(grow)) {
#pragma unroll
            for (int nt = 0; nt < 2; ++nt)
#pragma unroll
                for (int r = 0; r < 4; ++r) {
                    const float mnew  = fmaxf(mold[nt][r], rmax[nt][r]);
                    const float alpha = EXP2(mold[nt][r] - mnew);
                    mold[nt][r] = mnew;
                    lsum[nt][r] *= alpha;
#pragma unroll
                    for (int ct = 0; ct < 8; ++ct)
                        Oc[nt][ct][r] *= alpha;
                }
        }
#pragma unroll
        for (int nt = 0; nt < 2; ++nt)
#pragma unroll
            for (int r = 0; r < 4; ++r) {
                const float p0 = EXP2(sacc[nt][0][r] - mold[nt][r]);
                const float p1 = EXP2(sacc[nt][1][r] - mold[nt][r]);
                lsum[nt][r] += p0 + p1;
                const int row = nt * 16 + l4 * 4 + r;
                Ps[wv][row][l15]      = __builtin_bit_cast(u16, (_Float16)p0);
                Ps[wv][row][16 + l15] = __builtin_bit_cast(u16, (_Float16)p1);
            }
        asm volatile("s_waitcnt lgkmcnt(0)" ::: "memory");   // wave-private Ps

        // ---- PV: O += P @ V
        const half8 pf0 = *(const half8*)&Ps[wv][l15][l4 * 8];
        const half8 pf1 = *(const half8*)&Ps[wv][16 + l15][l4 * 8];
        __builtin_amdgcn_s_setprio(1);
#pragma unroll
        for (int ct = 0; ct < 8; ++ct) {
            Oc[0][ct] = __builtin_amdgcn_mfma_f32_16x16x32_f16(pf0, vf[ct], Oc[0][ct], 0, 0, 0);
            Oc[1][ct] = __builtin_amdgcn_mfma_f32_16x16x32_f16(pf1, vf[ct], Oc[1][ct], 0, 0, 0);
        }
        __builtin_amdgcn_s_setprio(0);

        // ---- issue next V tile (branch-free; hides under next QK + softmax)
        {
            const u16* vn = vbase + moff;
#pragma unroll
            for (int ct = 0; ct < 8; ++ct)
                vf[ct] = *(const half8*)(vn + (size_t)ct * 16 * NPB);
        }
    }

    // ---- full row sums across the 16 column-lanes (once, DPP)
#pragma unroll
    for (int nt = 0; nt < 2; ++nt)
#pragma unroll
        for (int r = 0; r < 4; ++r)
            lsum[nt][r] = dpp_row_sum(lsum[nt][r]);

    // ---- publish per-wave (m, l) per row
    if (l15 == 0) {
#pragma unroll
        for (int nt = 0; nt < 2; ++nt)
#pragma unroll
            for (int r = 0; r < 4; ++r) {
                const int row = nt * 16 + l4 * 4 + r;
                ml[wv][0][row] = mold[nt][r];
                ml[wv][1][row] = lsum[nt][r];
            }
    }
    __syncthreads();                      // ml visible; Ps region now dead

    // ---- global max frame per row, scale factors for own partial
    float f[2][4];
#pragma unroll
    for (int nt = 0; nt < 2; ++nt)
#pragma unroll
        for (int r = 0; r < 4; ++r) {
            const int row = nt * 16 + l4 * 4 + r;
            float M = ml[0][0][row];
#pragma unroll
            for (int w = 1; w < 8; ++w) M = fmaxf(M, ml[w][0][row]);
            f[nt][r] = EXP2(mold[nt][r] - M);
        }

    // ---- additive 8->4 merge into Obuf (two stages)
    if (wv >= 4) {
#pragma unroll
        for (int nt = 0; nt < 2; ++nt)
#pragma unroll
            for (int r = 0; r < 4; ++r) {
                const int row = nt * 16 + l4 * 4 + r;
#pragma unroll
                for (int ct = 0; ct < 8; ++ct)
                    Obuf[wv - 4][row][ct * 16 + l15] = Oc[nt][ct][r] * f[nt][r];
            }
    }
    __syncthreads();
    if (wv < 4) {
#pragma unroll
        for (int nt = 0; nt < 2; ++nt)
#pragma unroll
            for (int r = 0; r < 4; ++r) {
                const int row = nt * 16 + l4 * 4 + r;
#pragma unroll
                for (int ct = 0; ct < 8; ++ct)
                    Obuf[wv][row][ct * 16 + l15] += Oc[nt][ct][r] * f[nt][r];
            }
    }
    __syncthreads();

    // ---- final 4-way merge: wave wv handles rows [wv*4, wv*4+4), 16 lanes/row
    {
        const int row = wv * 4 + l4;
        const int c0  = l15 * 8;
        float M = ml[0][0][row];
#pragma unroll
        for (int w = 1; w < 8; ++w) M = fmaxf(M, ml[w][0][row]);
        float L = 0.f;
#pragma unroll
        for (int w = 0; w < 8; ++w)
            L += ml[w][1][row] * EXP2(ml[w][0][row] - M);
        const float invL = 1.f / L;
        const int grow_ = gr0 + row;
#pragma unroll
        for (int j = 0; j < 2; ++j) {
            const int c = c0 + j * 4;
            f32x4 a = *(const f32x4*)&Obuf[0][row][c];
#pragma unroll
            for (int w = 1; w < 4; ++w) {
                const f32x4 b = *(const f32x4*)&Obuf[w][row][c];
                a[0] += b[0]; a[1] += b[1]; a[2] += b[2]; a[3] += b[3];
            }
            const float4 sc = *(const float4*)&Sc[(size_t)grow_ * D + c];
            float4 o;
            o.x = a[0] * invL + sc.x;
            o.y = a[1] * invL + sc.y;
            o.z = a[2] * invL + sc.z;
            o.w = a[3] * invL + sc.w;
            *(float4*)&out[(size_t)grow_ * D + c] = o;
        }
    }
}

extern "C" void kernel_launch(void* const* d_in, const int* in_sizes, int n_in,
                              void* d_out, int out_size, void* d_ws, size_t ws_size,
                              hipStream_t stream) {
    const float* x  = (const float*)d_in[0];
    const float* Wk = (const float*)d_in[1];
    const float* bk = (const float*)d_in[2];
    const float* Wq = (const float*)d_in[3];
    const float* bq = (const float*)d_in[4];
    const float* Wv = (const float*)d_in[5];
    const float* bv = (const float*)d_in[6];
    const float* Ws = (const float*)d_in[7];
    const float* bs = (const float*)d_in[8];
    float* out = (float*)d_out;

    u16*   Kh = (u16*)d_ws;                       // 4 MB fp16 (log2e-scaled)
    u16*   Qh = Kh + (size_t)BN * D;              // 4 MB fp16
    u16*   Vt = Qh + (size_t)BN * D;              // 4 MB fp16, [b][c][m]
    float* Sc = (float*)(Vt + (size_t)BN * D);    // 8 MB fp32
    u16*   Wt = (u16*)(Sc + (size_t)BN * D);      // 256 KB fp16 W^T (4 mats)

    prep_kernel<<<128, 256, 0, stream>>>(Wk, Wq, Wv, Ws, Wt);
    proj_kernel<<<dim3(128, 4), 256, 0, stream>>>(x, Wt, bk, bq, bv, bs,
                                                  Kh, Qh, Vt, Sc);
    attn_kernel<<<512, 512, 0, stream>>>(Kh, Qh, Vt, Sc, out);
}

// Round 3
// 436.308 us; speedup vs baseline: 1.0155x; 1.0155x over previous
//
#include <hip/hip_runtime.h>
#include <math.h>

typedef unsigned short u16;
typedef __attribute__((ext_vector_type(8))) _Float16 half8;    // 8 fp16
typedef __attribute__((ext_vector_type(4))) _Float16 half4;    // 4 fp16
typedef __attribute__((ext_vector_type(4))) float    f32x4;

#define BATCH 4
#define NPB   4096      // pixels per batch (H*W)
#define BN    16384     // BATCH * NPB
#define CC    256       // input channels
#define D     128       // output channels (C/2)
#define LOG2E 1.44269504088896f
#define THR   8.0f      // deferred-rescale threshold (exp2 domain; P <= 256 in fp16)

#if __has_builtin(__builtin_amdgcn_exp2f)
#define EXP2(x) __builtin_amdgcn_exp2f(x)
#else
#define EXP2(x) exp2f(x)
#endif

// 16-lane (DPP row) reductions on the VALU pipe — no LDS crossbar.
template<int CTRL>
__device__ __forceinline__ float dpp_mov(float x) {
    return __builtin_bit_cast(float, __builtin_amdgcn_update_dpp(
        __builtin_bit_cast(int, x), __builtin_bit_cast(int, x),
        CTRL, 0xf, 0xf, false));
}
__device__ __forceinline__ float dpp_row_max(float x) {
    x = fmaxf(x, dpp_mov<0x128>(x));   // row_ror:8
    x = fmaxf(x, dpp_mov<0x124>(x));   // row_ror:4
    x = fmaxf(x, dpp_mov<0x122>(x));   // row_ror:2
    x = fmaxf(x, dpp_mov<0x121>(x));   // row_ror:1
    return x;
}
__device__ __forceinline__ float dpp_row_sum(float x) {
    x += dpp_mov<0x128>(x);
    x += dpp_mov<0x124>(x);
    x += dpp_mov<0x122>(x);
    x += dpp_mov<0x121>(x);
    return x;
}

// ---------------------------------------------------------------------------
// Prep: W[mat] (f32 [256][128]) -> Wt[mat][c][k] fp16 (c-major, contiguous k).
// mat 0 (K) pre-scaled by log2e. 128 blocks x 256 threads x 4 elements.
// ---------------------------------------------------------------------------
__global__ __launch_bounds__(256) void prep_kernel(
    const float* __restrict__ Wk, const float* __restrict__ Wq,
    const float* __restrict__ Wv, const float* __restrict__ Ws,
    u16* __restrict__ Wt)
{
    const int f   = (blockIdx.x * 256 + threadIdx.x) * 4;   // flat output idx
    const int mat = f >> 15;
    const int rem = f & 32767;
    const int c   = rem >> 8;
    const int k0  = rem & 255;
    const float* W = (mat == 0) ? Wk : (mat == 1) ? Wq : (mat == 2) ? Wv : Ws;
    const float scale = (mat == 0) ? LOG2E : 1.0f;
    _Float16 t4[4];
#pragma unroll
    for (int i = 0; i < 4; ++i)
        t4[i] = (_Float16)(W[(size_t)(k0 + i) * D + c] * scale);
    *(uint2*)&Wt[(size_t)mat * 32768 + (size_t)c * 256 + k0] = *(const uint2*)t4;
}

// ---------------------------------------------------------------------------
// Projection: grid (128, 4) = 128-pixel x-tile x one matrix per block.
// (unchanged — isolated this round; next target once attn lands)
// ---------------------------------------------------------------------------
#define APJ 264         // As row pitch in u16 (528 B: 16B-aligned, 4-bank row shift)

__global__ __launch_bounds__(256, 2) void proj_kernel(
    const float* __restrict__ x, const u16* __restrict__ Wt,
    const float* __restrict__ bk, const float* __restrict__ bq,
    const float* __restrict__ bv, const float* __restrict__ bs,
    u16* __restrict__ Kh, u16* __restrict__ Qh,
    u16* __restrict__ Vt, float* __restrict__ Sc)
{
    __shared__ __align__(16) u16 As[128][APJ];   // 66 KB -> 2 blocks/CU

    const int tid = threadIdx.x;
    const int wv  = tid >> 6;
    const int l   = tid & 63;
    const int l15 = l & 15;
    const int l4  = l >> 4;
    const int by  = blockIdx.y;
    const int gm0 = blockIdx.x * 128;
    const int c0  = wv * 32;

    // ---- W fragments from Wt: wf[ct][kc], lane -> W[k=kc*32+l4*8..+8][c0+ct*16+l15]
    const u16* wb = Wt + (size_t)by * 32768 + (size_t)(c0 + l15) * 256 + l4 * 8;
    half8 wf[2][8];
#pragma unroll
    for (int ct = 0; ct < 2; ++ct)
#pragma unroll
        for (int kc = 0; kc < 8; ++kc)
            wf[ct][kc] = *(const half8*)(wb + ct * 16 * 256 + kc * 32);

    // ---- stage the 128x256 x-tile once (coalesced: thread t -> float4 i*256+t)
    {
        const float4* xg = (const float4*)(x + (size_t)gm0 * CC);
#pragma unroll 8
        for (int i = 0; i < 32; ++i) {
            const int f = i * 256 + tid;           // flat float4 index
            const float4 v = xg[f];
            const int row = f >> 6, col4 = f & 63;
            _Float16 h[4] = {(_Float16)v.x, (_Float16)v.y,
                             (_Float16)v.z, (_Float16)v.w};
            *(uint2*)&As[row][col4 * 4] = *(const uint2*)h;
        }
    }
    __syncthreads();

    f32x4 acc[8][2];
#pragma unroll
    for (int mt = 0; mt < 8; ++mt) {
        acc[mt][0] = (f32x4){0.f, 0.f, 0.f, 0.f};
        acc[mt][1] = (f32x4){0.f, 0.f, 0.f, 0.f};
    }

    if (by == 2) {
        for (int kc = 0; kc < 8; ++kc)
#pragma unroll
            for (int mt = 0; mt < 8; ++mt) {
                const half8 a = *(const half8*)&As[mt * 16 + l15][kc * 32 + l4 * 8];
                acc[mt][0] = __builtin_amdgcn_mfma_f32_16x16x32_f16(a, wf[0][kc], acc[mt][0], 0, 0, 0);
                acc[mt][1] = __builtin_amdgcn_mfma_f32_16x16x32_f16(a, wf[1][kc], acc[mt][1], 0, 0, 0);
            }
        // V: D[m][c]; fp16 transposed [batch][c][m], pack 4 consecutive m
        const float bb[2] = {bv[c0 + l15], bv[c0 + 16 + l15]};
        const int batch = gm0 >> 12;
        const int mb0   = (gm0 & 4095) + l4 * 4;
        u16* vbp = Vt + (size_t)batch * (D * NPB);
#pragma unroll
        for (int mt = 0; mt < 8; ++mt)
#pragma unroll
            for (int ct = 0; ct < 2; ++ct) {
                const int c = c0 + ct * 16 + l15;
                _Float16 t4[4];
#pragma unroll
                for (int r = 0; r < 4; ++r)
                    t4[r] = (_Float16)(acc[mt][ct][r] + bb[ct]);
                *(uint2*)&vbp[(size_t)c * NPB + mb0 + mt * 16] = *(const uint2*)t4;
            }
    } else {
        for (int kc = 0; kc < 8; ++kc)
#pragma unroll
            for (int mt = 0; mt < 8; ++mt) {
                const half8 a = *(const half8*)&As[mt * 16 + l15][kc * 32 + l4 * 8];
                acc[mt][0] = __builtin_amdgcn_mfma_f32_16x16x32_f16(wf[0][kc], a, acc[mt][0], 0, 0, 0);
                acc[mt][1] = __builtin_amdgcn_mfma_f32_16x16x32_f16(wf[1][kc], a, acc[mt][1], 0, 0, 0);
            }
        // swapped: D[c][m] — lane holds c = c0+ct*16+l4*4+r, m = gm0+mt*16+l15
        if (by == 3) {
            float bb2[2][4];
#pragma unroll
            for (int ct = 0; ct < 2; ++ct)
#pragma unroll
                for (int r = 0; r < 4; ++r)
                    bb2[ct][r] = bs[c0 + ct * 16 + l4 * 4 + r];
#pragma unroll
            for (int mt = 0; mt < 8; ++mt) {
                const int m = gm0 + mt * 16 + l15;
#pragma unroll
                for (int ct = 0; ct < 2; ++ct) {
                    float4 v;
                    v.x = acc[mt][ct][0] + bb2[ct][0];
                    v.y = acc[mt][ct][1] + bb2[ct][1];
                    v.z = acc[mt][ct][2] + bb2[ct][2];
                    v.w = acc[mt][ct][3] + bb2[ct][3];
                    *(float4*)&Sc[(size_t)m * D + c0 + ct * 16 + l4 * 4] = v;
                }
            }
        } else {
            const float* bsrc = (by == 0) ? bk : bq;
            const float scale = (by == 0) ? LOG2E : 1.0f;   // Wt already scaled
            u16* O = (by == 0) ? Kh : Qh;
            float bb2[2][4];
#pragma unroll
            for (int ct = 0; ct < 2; ++ct)
#pragma unroll
                for (int r = 0; r < 4; ++r)
                    bb2[ct][r] = bsrc[c0 + ct * 16 + l4 * 4 + r] * scale;
#pragma unroll
            for (int mt = 0; mt < 8; ++mt) {
                const int m = gm0 + mt * 16 + l15;
#pragma unroll
                for (int ct = 0; ct < 2; ++ct) {
                    _Float16 t4[4];
#pragma unroll
                    for (int r = 0; r < 4; ++r)
                        t4[r] = (_Float16)(acc[mt][ct][r] + bb2[ct][r]);
                    *(uint2*)&O[(size_t)m * D + c0 + ct * 16 + l4 * 4] =
                        *(const uint2*)t4;
                }
            }
        }
    }
}

// ---------------------------------------------------------------------------
// Flash attention v4: barrier-free main loop, global->register fragments,
// sized to fit 128 VGPRs -> 16 waves/CU (4 waves/SIMD latency hiding).
// 512 blocks x 32 n-rows; 8 waves = (n-half, m-quarter): each wave computes
// 16 n x 1024 m in 64 iters of 16-m tiles. QK via 16x16x32 MFMA, PV via
// 16x16x16 MFMA (half4 fragments). Waves wv and wv^1 share Q/V addresses
// (L1 reuse). Deferred rescale (THR=8, exp2 domain). One-stage 8-slot merge.
// ---------------------------------------------------------------------------
#define VP  24          // Ps row pitch (u16): 48 B
#define OBP 132         // Obuf row pitch (f32): 528 B, 16B-aligned, bank shift 4

__global__ __launch_bounds__(512, 2) void attn_kernel(
    const u16* __restrict__ Kh, const u16* __restrict__ Qh,
    const u16* __restrict__ Vt, const float* __restrict__ Sc,
    float* __restrict__ out)
{
    __shared__ __align__(16) u16   Ps[8][16][VP];     // 6 KB, wave-private P
    __shared__ __align__(16) float Obuf[8][16][OBP];  // 67.6 KB merge slots
    __shared__ __align__(16) float ml[8][2][16];      // 1 KB (m, l) per slot
    // total 74.7 KB -> 2 blocks/CU

    const int tid = threadIdx.x;
    const int wv  = tid >> 6;          // 0..7
    const int l   = tid & 63;
    const int l15 = l & 15;
    const int l4  = l >> 4;
    const int nh  = wv & 1;            // n-half (0..1)
    const int mq  = wv >> 1;           // m-quarter (0..3)

    // XCD-affinity remap: round-robin dispatch puts bx%8 on XCD bx%8 ->
    // each XCD pair serves one batch (K+Q+V ~3 MB fits the 4 MB per-XCD L2).
    const int bx    = blockIdx.x;
    const int xcd   = bx & 7;
    const int batch = xcd >> 1;
    const int tile  = ((xcd & 1) << 6) | (bx >> 3);
    const int gr0   = batch * NPB + tile * 32;      // block's 32 K-rows
    const int gn0   = gr0 + nh * 16;                // wave's 16 K-rows

    // ---- K fragments straight from global (log2e pre-scaled), held all loop
    half8 kf[4];
    {
        const u16* kb = Kh + (size_t)(gn0 + l15) * D + l4 * 8;
#pragma unroll
        for (int kc = 0; kc < 4; ++kc)
            kf[kc] = *(const half8*)(kb + kc * 32);
    }

    // ---- per-wave 1024-m quarter base pointers
    const u16* qbase = Qh + (size_t)(batch * NPB + mq * 1024 + l15) * D + l4 * 8;
    const u16* vbase = Vt + (size_t)batch * NPB * D + (size_t)l15 * NPB
                       + mq * 1024 + l4 * 4;

    // ---- prologue fragment loads (it = 0)
    half8 qf[4];
    half4 vf[8];
#pragma unroll
    for (int kc = 0; kc < 4; ++kc)
        qf[kc] = *(const half8*)(qbase + kc * 32);
#pragma unroll
    for (int ct = 0; ct < 8; ++ct)
        vf[ct] = *(const half4*)(vbase + (size_t)ct * 16 * NPB);

    f32x4 Oc[8];
#pragma unroll
    for (int ct = 0; ct < 8; ++ct) Oc[ct] = (f32x4){0.f, 0.f, 0.f, 0.f};
    float mold[4], lsum[4];
#pragma unroll
    for (int r = 0; r < 4; ++r) { mold[r] = -1e30f; lsum[r] = 0.f; }

    for (int it = 0; it < 64; ++it) {
        const int nx = (it + 1) & 63;          // wrap: branch-free prefetch

        // ---- S' = (K*log2e) @ Q^T : 16n x 16m, exp2 domain
        f32x4 sacc = (f32x4){0.f, 0.f, 0.f, 0.f};
        __builtin_amdgcn_s_setprio(1);
#pragma unroll
        for (int kc = 0; kc < 4; ++kc)
            sacc = __builtin_amdgcn_mfma_f32_16x16x32_f16(kf[kc], qf[kc], sacc, 0, 0, 0);
        __builtin_amdgcn_s_setprio(0);

        // ---- issue next Q tile (hides under softmax + PV)
        {
            const u16* qn = qbase + (size_t)nx * 16 * D;
#pragma unroll
            for (int kc = 0; kc < 4; ++kc)
                qf[kc] = *(const half8*)(qn + kc * 32);
        }

        // ---- online softmax (rows n = l4*4+r, reduce over 16 m-lanes)
        float rmax[4];
        int grow = 0;
#pragma unroll
        for (int r = 0; r < 4; ++r) {
            rmax[r] = dpp_row_max(sacc[r]);
            grow |= (rmax[r] > mold[r] + THR) ? 1 : 0;
        }
        if (__any(grow)) {
#pragma unroll
            for (int r = 0; r < 4; ++r) {
                const float mnew  = fmaxf(mold[r], rmax[r]);
                const float alpha = EXP2(mold[r] - mnew);
                mold[r] = mnew;
                lsum[r] *= alpha;
#pragma unroll
                for (int ct = 0; ct < 8; ++ct) Oc[ct][r] *= alpha;
            }
        }
#pragma unroll
        for (int r = 0; r < 4; ++r) {
            const float p = EXP2(sacc[r] - mold[r]);
            lsum[r] += p;
            Ps[wv][l4 * 4 + r][l15] = __builtin_bit_cast(u16, (_Float16)p);
        }
        asm volatile("s_waitcnt lgkmcnt(0)" ::: "memory");   // wave-private Ps

        // ---- PV: O += P @ V (16x16x16, half4 fragments)
        const half4 pf = *(const half4*)&Ps[wv][l15][l4 * 4];
        __builtin_amdgcn_s_setprio(1);
#pragma unroll
        for (int ct = 0; ct < 8; ++ct)
            Oc[ct] = __builtin_amdgcn_mfma_f32_16x16x16f16(pf, vf[ct], Oc[ct], 0, 0, 0);
        __builtin_amdgcn_s_setprio(0);

        // ---- issue next V tile (hides under next QK + softmax)
        {
            const u16* vn = vbase + nx * 16;
#pragma unroll
            for (int ct = 0; ct < 8; ++ct)
                vf[ct] = *(const half4*)(vn + (size_t)ct * 16 * NPB);
        }
    }

    // ---- full row sums across the 16 column-lanes (once, DPP)
#pragma unroll
    for (int r = 0; r < 4; ++r) lsum[r] = dpp_row_sum(lsum[r]);

    // ---- publish per-wave (m, l) per row
    if (l15 == 0) {
#pragma unroll
        for (int r = 0; r < 4; ++r) {
            ml[wv][0][l4 * 4 + r] = mold[r];
            ml[wv][1][l4 * 4 + r] = lsum[r];
        }
    }
    __syncthreads();

    // ---- scale own partial into common max-frame (per n-half), write slot
#pragma unroll
    for (int r = 0; r < 4; ++r) {
        const int row = l4 * 4 + r;
        const float M = fmaxf(fmaxf(ml[nh][0][row],     ml[nh + 2][0][row]),
                              fmaxf(ml[nh + 4][0][row], ml[nh + 6][0][row]));
        const float f = EXP2(mold[r] - M);
#pragma unroll
        for (int ct = 0; ct < 8; ++ct)
            Obuf[wv][row][ct * 16 + l15] = Oc[ct][r] * f;
    }
    __syncthreads();

    // ---- final merge: wave wv -> out-rows [wv*4, wv*4+4), 16 lanes/row
    {
        const int orow = wv * 4 + l4;          // 0..31 within block tile
        const int nh2  = orow >> 4;
        const int rloc = orow & 15;
        const float M = fmaxf(fmaxf(ml[nh2][0][rloc],     ml[nh2 + 2][0][rloc]),
                              fmaxf(ml[nh2 + 4][0][rloc], ml[nh2 + 6][0][rloc]));
        float L = 0.f;
#pragma unroll
        for (int k = 0; k < 4; ++k)
            L += ml[nh2 + 2 * k][1][rloc] * EXP2(ml[nh2 + 2 * k][0][rloc] - M);
        const float invL = 1.f / L;
        const int grow_ = gr0 + orow;
#pragma unroll
        for (int j = 0; j < 2; ++j) {
            const int c = l15 * 8 + j * 4;
            f32x4 a = *(const f32x4*)&Obuf[nh2][rloc][c];
#pragma unroll
            for (int k = 1; k < 4; ++k) {
                const f32x4 b = *(const f32x4*)&Obuf[nh2 + 2 * k][rloc][c];
                a[0] += b[0]; a[1] += b[1]; a[2] += b[2]; a[3] += b[3];
            }
            const float4 sc = *(const float4*)&Sc[(size_t)grow_ * D + c];
            float4 o;
            o.x = a[0] * invL + sc.x;
            o.y = a[1] * invL + sc.y;
            o.z = a[2] * invL + sc.z;
            o.w = a[3] * invL + sc.w;
            *(float4*)&out[(size_t)grow_ * D + c] = o;
        }
    }
}

extern "C" void kernel_launch(void* const* d_in, const int* in_sizes, int n_in,
                              void* d_out, int out_size, void* d_ws, size_t ws_size,
                              hipStream_t stream) {
    const float* x  = (const float*)d_in[0];
    const float* Wk = (const float*)d_in[1];
    const float* bk = (const float*)d_in[2];
    const float* Wq = (const float*)d_in[3];
    const float* bq = (const float*)d_in[4];
    const float* Wv = (const float*)d_in[5];
    const float* bv = (const float*)d_in[6];
    const float* Ws = (const float*)d_in[7];
    const float* bs = (const float*)d_in[8];
    float* out = (float*)d_out;

    u16*   Kh = (u16*)d_ws;                       // 4 MB fp16 (log2e-scaled)
    u16*   Qh = Kh + (size_t)BN * D;              // 4 MB fp16
    u16*   Vt = Qh + (size_t)BN * D;              // 4 MB fp16, [b][c][m]
    float* Sc = (float*)(Vt + (size_t)BN * D);    // 8 MB fp32
    u16*   Wt = (u16*)(Sc + (size_t)BN * D);      // 256 KB fp16 W^T (4 mats)

    prep_kernel<<<128, 256, 0, stream>>>(Wk, Wq, Wv, Ws, Wt);
    proj_kernel<<<dim3(128, 4), 256, 0, stream>>>(x, Wt, bk, bq, bv, bs,
                                                  Kh, Qh, Vt, Sc);
    attn_kernel<<<512, 512, 0, stream>>>(Kh, Qh, Vt, Sc, out);
}

// Round 4
// 191.007 us; speedup vs baseline: 2.3196x; 2.2843x over previous
//
#include <hip/hip_runtime.h>
#include <math.h>

typedef unsigned short u16;
typedef __attribute__((ext_vector_type(8))) _Float16 half8;    // 8 fp16
typedef __attribute__((ext_vector_type(4))) float    f32x4;

#define BATCH 4
#define NPB   4096      // pixels per batch (H*W)
#define BN    16384     // BATCH * NPB
#define CC    256       // input channels
#define D     128       // output channels (C/2)
#define LOG2E 1.44269504088896f

#if __has_builtin(__builtin_amdgcn_exp2f)
#define EXP2(x) __builtin_amdgcn_exp2f(x)
#else
#define EXP2(x) exp2f(x)
#endif

// 16-lane (DPP row) reductions on the VALU pipe — no LDS crossbar.
template<int CTRL>
__device__ __forceinline__ float dpp_mov(float x) {
    return __builtin_bit_cast(float, __builtin_amdgcn_update_dpp(
        __builtin_bit_cast(int, x), __builtin_bit_cast(int, x),
        CTRL, 0xf, 0xf, false));
}
__device__ __forceinline__ float dpp_row_max(float x) {
    x = fmaxf(x, dpp_mov<0x128>(x));   // row_ror:8
    x = fmaxf(x, dpp_mov<0x124>(x));   // row_ror:4
    x = fmaxf(x, dpp_mov<0x122>(x));   // row_ror:2
    x = fmaxf(x, dpp_mov<0x121>(x));   // row_ror:1
    return x;
}
__device__ __forceinline__ float dpp_row_sum(float x) {
    x += dpp_mov<0x128>(x);
    x += dpp_mov<0x124>(x);
    x += dpp_mov<0x122>(x);
    x += dpp_mov<0x121>(x);
    return x;
}

// ---------------------------------------------------------------------------
// Prep: W[mat] (f32 [256][128]) -> Wt[mat][c][k] fp16 (c-major, contiguous k).
// mat 0 (K) pre-scaled by log2e. 128 blocks x 256 threads x 4 elements.
// ---------------------------------------------------------------------------
__global__ __launch_bounds__(256) void prep_kernel(
    const float* __restrict__ Wk, const float* __restrict__ Wq,
    const float* __restrict__ Wv, const float* __restrict__ Ws,
    u16* __restrict__ Wt)
{
    const int f   = (blockIdx.x * 256 + threadIdx.x) * 4;   // flat output idx
    const int mat = f >> 15;
    const int rem = f & 32767;
    const int c   = rem >> 8;
    const int k0  = rem & 255;
    const float* W = (mat == 0) ? Wk : (mat == 1) ? Wq : (mat == 2) ? Wv : Ws;
    const float scale = (mat == 0) ? LOG2E : 1.0f;
    _Float16 t4[4];
#pragma unroll
    for (int i = 0; i < 4; ++i)
        t4[i] = (_Float16)(W[(size_t)(k0 + i) * D + c] * scale);
    *(uint2*)&Wt[(size_t)mat * 32768 + (size_t)c * 256 + k0] = *(const uint2*)t4;
}

// ---------------------------------------------------------------------------
// Projection: grid (128, 4) = 128-pixel x-tile x one matrix per block.
// (unchanged — next target once attn lands)
// ---------------------------------------------------------------------------
#define APJ 264         // As row pitch in u16 (528 B: 16B-aligned, 4-bank row shift)

__global__ __launch_bounds__(256, 2) void proj_kernel(
    const float* __restrict__ x, const u16* __restrict__ Wt,
    const float* __restrict__ bk, const float* __restrict__ bq,
    const float* __restrict__ bv, const float* __restrict__ bs,
    u16* __restrict__ Kh, u16* __restrict__ Qh,
    u16* __restrict__ Vt, float* __restrict__ Sc)
{
    __shared__ __align__(16) u16 As[128][APJ];   // 66 KB -> 2 blocks/CU

    const int tid = threadIdx.x;
    const int wv  = tid >> 6;
    const int l   = tid & 63;
    const int l15 = l & 15;
    const int l4  = l >> 4;
    const int by  = blockIdx.y;
    const int gm0 = blockIdx.x * 128;
    const int c0  = wv * 32;

    // ---- W fragments from Wt: wf[ct][kc], lane -> W[k=kc*32+l4*8..+8][c0+ct*16+l15]
    const u16* wb = Wt + (size_t)by * 32768 + (size_t)(c0 + l15) * 256 + l4 * 8;
    half8 wf[2][8];
#pragma unroll
    for (int ct = 0; ct < 2; ++ct)
#pragma unroll
        for (int kc = 0; kc < 8; ++kc)
            wf[ct][kc] = *(const half8*)(wb + ct * 16 * 256 + kc * 32);

    // ---- stage the 128x256 x-tile once (coalesced: thread t -> float4 i*256+t)
    {
        const float4* xg = (const float4*)(x + (size_t)gm0 * CC);
#pragma unroll 8
        for (int i = 0; i < 32; ++i) {
            const int f = i * 256 + tid;           // flat float4 index
            const float4 v = xg[f];
            const int row = f >> 6, col4 = f & 63;
            _Float16 h[4] = {(_Float16)v.x, (_Float16)v.y,
                             (_Float16)v.z, (_Float16)v.w};
            *(uint2*)&As[row][col4 * 4] = *(const uint2*)h;
        }
    }
    __syncthreads();

    f32x4 acc[8][2];
#pragma unroll
    for (int mt = 0; mt < 8; ++mt) {
        acc[mt][0] = (f32x4){0.f, 0.f, 0.f, 0.f};
        acc[mt][1] = (f32x4){0.f, 0.f, 0.f, 0.f};
    }

    if (by == 2) {
        for (int kc = 0; kc < 8; ++kc)
#pragma unroll
            for (int mt = 0; mt < 8; ++mt) {
                const half8 a = *(const half8*)&As[mt * 16 + l15][kc * 32 + l4 * 8];
                acc[mt][0] = __builtin_amdgcn_mfma_f32_16x16x32_f16(a, wf[0][kc], acc[mt][0], 0, 0, 0);
                acc[mt][1] = __builtin_amdgcn_mfma_f32_16x16x32_f16(a, wf[1][kc], acc[mt][1], 0, 0, 0);
            }
        // V: D[m][c]; fp16 transposed [batch][c][m], pack 4 consecutive m
        const float bb[2] = {bv[c0 + l15], bv[c0 + 16 + l15]};
        const int batch = gm0 >> 12;
        const int mb0   = (gm0 & 4095) + l4 * 4;
        u16* vbp = Vt + (size_t)batch * (D * NPB);
#pragma unroll
        for (int mt = 0; mt < 8; ++mt)
#pragma unroll
            for (int ct = 0; ct < 2; ++ct) {
                const int c = c0 + ct * 16 + l15;
                _Float16 t4[4];
#pragma unroll
                for (int r = 0; r < 4; ++r)
                    t4[r] = (_Float16)(acc[mt][ct][r] + bb[ct]);
                *(uint2*)&vbp[(size_t)c * NPB + mb0 + mt * 16] = *(const uint2*)t4;
            }
    } else {
        for (int kc = 0; kc < 8; ++kc)
#pragma unroll
            for (int mt = 0; mt < 8; ++mt) {
                const half8 a = *(const half8*)&As[mt * 16 + l15][kc * 32 + l4 * 8];
                acc[mt][0] = __builtin_amdgcn_mfma_f32_16x16x32_f16(wf[0][kc], a, acc[mt][0], 0, 0, 0);
                acc[mt][1] = __builtin_amdgcn_mfma_f32_16x16x32_f16(wf[1][kc], a, acc[mt][1], 0, 0, 0);
            }
        // swapped: D[c][m] — lane holds c = c0+ct*16+l4*4+r, m = gm0+mt*16+l15
        if (by == 3) {
            float bb2[2][4];
#pragma unroll
            for (int ct = 0; ct < 2; ++ct)
#pragma unroll
                for (int r = 0; r < 4; ++r)
                    bb2[ct][r] = bs[c0 + ct * 16 + l4 * 4 + r];
#pragma unroll
            for (int mt = 0; mt < 8; ++mt) {
                const int m = gm0 + mt * 16 + l15;
#pragma unroll
                for (int ct = 0; ct < 2; ++ct) {
                    float4 v;
                    v.x = acc[mt][ct][0] + bb2[ct][0];
                    v.y = acc[mt][ct][1] + bb2[ct][1];
                    v.z = acc[mt][ct][2] + bb2[ct][2];
                    v.w = acc[mt][ct][3] + bb2[ct][3];
                    *(float4*)&Sc[(size_t)m * D + c0 + ct * 16 + l4 * 4] = v;
                }
            }
        } else {
            const float* bsrc = (by == 0) ? bk : bq;
            const float scale = (by == 0) ? LOG2E : 1.0f;   // Wt already scaled
            u16* O = (by == 0) ? Kh : Qh;
            float bb2[2][4];
#pragma unroll
            for (int ct = 0; ct < 2; ++ct)
#pragma unroll
                for (int r = 0; r < 4; ++r)
                    bb2[ct][r] = bsrc[c0 + ct * 16 + l4 * 4 + r] * scale;
#pragma unroll
            for (int mt = 0; mt < 8; ++mt) {
                const int m = gm0 + mt * 16 + l15;
#pragma unroll
                for (int ct = 0; ct < 2; ++ct) {
                    _Float16 t4[4];
#pragma unroll
                    for (int r = 0; r < 4; ++r)
                        t4[r] = (_Float16)(acc[mt][ct][r] + bb2[ct][r]);
                    *(uint2*)&O[(size_t)m * D + c0 + ct * 16 + l4 * 4] =
                        *(const uint2*)t4;
                }
            }
        }
    }
}

// ---------------------------------------------------------------------------
// Flash attention v5 = proven round-0 inner loop, m-split x2 for occupancy.
// 1024 blocks (= 512 n-tiles x 2 m-halves) x 256 thr; LDS 51.7 KB -> 3
// blocks/CU resident (round-0 was grid-limited to 2). Each block: 32 n-rows,
// 32 iters x (2x32 m) over its 2048-m half. Writes un-normalized partial
// (O in own max-frame, M, L) to workspace; merge_kernel combines.
// ---------------------------------------------------------------------------
#define TM 32
#define QP 136          // Qs/Ks row pitch (u16)
#define VP 40           // Vs/Ps row pitch (u16)

__global__ __launch_bounds__(256, 3) void attn_kernel(
    const u16* __restrict__ Kh, const u16* __restrict__ Qh,
    const u16* __restrict__ Vt,
    float* __restrict__ Opart, float* __restrict__ mlpart)
{
    __shared__ __align__(16) unsigned char smem[51712];
    u16 (*Ks)[QP]     = (u16(*)[QP])(smem);                 // 32 x 136 (fp16)
    u16 (*Qs)[TM][QP] = (u16(*)[TM][QP])(smem + 8704);      // 2 x 32 x 136 (fp16)
    u16 (*Vs)[D][VP]  = (u16(*)[D][VP])(smem + 26112);      // 2 x 128 x 40 (fp16)
    u16 (*Ps)[16][VP] = (u16(*)[16][VP])(smem + 46592);     // 4 x 16 x 40 (fp16)

    const int tid = threadIdx.x;
    const int wv  = tid >> 6;
    const int l   = tid & 63;
    const int l15 = l & 15;
    const int l4  = l >> 4;

    // XCD-affinity remap (bijective on [0,1024)): round-robin dispatch puts
    // bx%8 on XCD bx%8 -> each XCD pair serves one batch (K+Q+V ~3 MB / L2).
    const int bx    = blockIdx.x;
    const int xcd   = bx & 7;
    const int batch = xcd >> 1;
    const int rest  = bx >> 3;                       // 0..127
    const int by    = rest & 1;                      // m-half (0/1)
    const int tile  = ((xcd & 1) << 6) | (rest >> 1);// 0..127
    const int gr0   = batch * NPB + tile * 32;       // block's 32 K-rows
    const int part  = (batch * 128 + tile) * 2 + by; // workspace slot

    const int n16 = wv & 1;                 // n-group
    const int mh  = wv >> 1;                // m-half within block

    // ---- stage K tile (32 x 128 fp16, already log2e-scaled)
    {
        const int row = tid >> 3, ch = tid & 7;
        const uint4* src = (const uint4*)(Kh + (size_t)(gr0 + row) * D + ch * 16);
        *(uint4*)&Ks[row][ch * 16]     = src[0];
        *(uint4*)&Ks[row][ch * 16 + 8] = src[1];
    }
    __syncthreads();

    half8 kf[4];
#pragma unroll
    for (int kc = 0; kc < 4; ++kc)
        kf[kc] = *(const half8*)&Ks[n16 * 16 + l15][kc * 32 + l4 * 8];

    f32x4 Oc[8];
#pragma unroll
    for (int ct = 0; ct < 8; ++ct) Oc[ct] = (f32x4){0.f, 0.f, 0.f, 0.f};
    float mold[4], lsum[4];
#pragma unroll
    for (int r = 0; r < 4; ++r) { mold[r] = -1e30f; lsum[r] = 0.f; }

    // per-wave staging sources: Q quarter (by*2 + wv), V quarter (by*2 + h)
    const u16* qsrc = Qh + (size_t)(batch * NPB + (by * 2 + wv) * 1024) * D; // wv<2
    const u16* vsrc = Vt + (size_t)batch * NPB * D;                 // c-major

    for (int it = 0; it < 32; ++it) {
        __syncthreads();
        const int m0 = it * TM;
        if (wv < 2) {
            const u16* s = qsrc + (size_t)m0 * D + l15 * 8;
#pragma unroll
            for (int j = 0; j < 8; ++j) {
                const int row = j * 4 + l4;
                const uint4 v = *(const uint4*)(s + (size_t)row * D);
                *(uint4*)&Qs[wv][row][l15 * 8] = v;
            }
        } else {
            const int h = wv - 2;
            const u16* s = vsrc + (size_t)((by * 2 + h) * 1024 + m0) + (l & 3) * 8;
#pragma unroll
            for (int j = 0; j < 8; ++j) {
                const int cc = j * 16 + (l >> 2);
                const uint4 v = *(const uint4*)(s + (size_t)cc * NPB);
                *(uint4*)&Vs[h][cc][(l & 3) * 8] = v;
            }
        }
        __syncthreads();

        // ---- S' = (K*log2e) @ Q^T (fp16 MFMA, log2-domain scores)
        f32x4 sacc[2];
        sacc[0] = (f32x4){0.f, 0.f, 0.f, 0.f};
        sacc[1] = (f32x4){0.f, 0.f, 0.f, 0.f};
#pragma unroll
        for (int kc = 0; kc < 4; ++kc) {
#pragma unroll
            for (int mt = 0; mt < 2; ++mt) {
                const half8 qf =
                    *(const half8*)&Qs[mh][mt * 16 + l15][kc * 32 + l4 * 8];
                sacc[mt] = __builtin_amdgcn_mfma_f32_16x16x32_f16(
                    kf[kc], qf, sacc[mt], 0, 0, 0);
            }
        }

        // ---- online softmax (exp2 domain): DPP row-max, unconditional rescale
#pragma unroll
        for (int r = 0; r < 4; ++r) {
            const float rmax  = dpp_row_max(fmaxf(sacc[0][r], sacc[1][r]));
            const float mnew  = fmaxf(mold[r], rmax);
            const float alpha = EXP2(mold[r] - mnew);
            mold[r] = mnew;
            const float p0 = EXP2(sacc[0][r] - mnew);
            const float p1 = EXP2(sacc[1][r] - mnew);
            lsum[r] = lsum[r] * alpha + p0 + p1;
#pragma unroll
            for (int ct = 0; ct < 8; ++ct) Oc[ct][r] *= alpha;
            Ps[wv][l4 * 4 + r][l15]      = __builtin_bit_cast(u16, (_Float16)p0);
            Ps[wv][l4 * 4 + r][16 + l15] = __builtin_bit_cast(u16, (_Float16)p1);
        }
        asm volatile("s_waitcnt lgkmcnt(0)" ::: "memory");   // wave-private Ps

        const half8 pf = *(const half8*)&Ps[wv][l15][l4 * 8];
#pragma unroll
        for (int ct = 0; ct < 8; ++ct) {
            const half8 vf = *(const half8*)&Vs[mh][ct * 16 + l15][l4 * 8];
            Oc[ct] = __builtin_amdgcn_mfma_f32_16x16x32_f16(pf, vf, Oc[ct], 0, 0, 0);
        }
    }

    // ---- final per-row sum across the 16 column-lanes (once, DPP)
#pragma unroll
    for (int r = 0; r < 4; ++r) lsum[r] = dpp_row_sum(lsum[r]);

    // ---- combine the two m-halves (waves wv and wv^2 share rows)
    __syncthreads();
    float (*Obuf)[16][D] = (float(*)[16][D])(smem);         // aliases Ks/Qs
    float* cmbM = (float*)(smem + 26112);                   // aliases Vs
    float* cmbL = (float*)(smem + 26368);

    if (l15 == 0) {
#pragma unroll
        for (int r = 0; r < 4; ++r) {
            cmbM[wv * 16 + l4 * 4 + r] = mold[r];
            cmbL[wv * 16 + l4 * 4 + r] = lsum[r];
        }
    }
    if (mh == 1) {
#pragma unroll
        for (int ct = 0; ct < 8; ++ct)
#pragma unroll
            for (int r = 0; r < 4; ++r)
                Obuf[n16][l4 * 4 + r][ct * 16 + l15] = Oc[ct][r];
    }
    __syncthreads();

    if (mh == 0) {
        float a0[4], a1[4], Mv[4], Lb[4];
#pragma unroll
        for (int r = 0; r < 4; ++r) {
            const int row = l4 * 4 + r;
            const float M1 = cmbM[(wv + 2) * 16 + row];
            const float L1 = cmbL[(wv + 2) * 16 + row];
            const float M  = fmaxf(mold[r], M1);
            a0[r] = EXP2(mold[r] - M);
            a1[r] = EXP2(M1 - M);
            Mv[r] = M;
            Lb[r] = lsum[r] * a0[r] + L1 * a1[r];
        }
        if (l15 == 0) {
#pragma unroll
            for (int r = 0; r < 4; ++r) {
                const int orow = n16 * 16 + l4 * 4 + r;
                mlpart[(size_t)part * 64 + orow]      = Mv[r];
                mlpart[(size_t)part * 64 + 32 + orow] = Lb[r];
            }
        }
#pragma unroll
        for (int ct = 0; ct < 8; ++ct) {
#pragma unroll
            for (int r = 0; r < 4; ++r) {
                const int row  = l4 * 4 + r;
                const int c    = ct * 16 + l15;
                const int orow = n16 * 16 + row;
                Opart[(size_t)part * 4096 + orow * D + c] =
                    Oc[ct][r] * a0[r] + Obuf[n16][row][c] * a1[r];
            }
        }
    }
}

// ---------------------------------------------------------------------------
// Merge: combine the 2 m-half partials per 32-row n-tile, normalize, add
// shortcut. 512 blocks x 256 thr; pure HBM-bound (~48 MB moved).
// ---------------------------------------------------------------------------
__global__ __launch_bounds__(256) void merge_kernel(
    const float* __restrict__ Opart, const float* __restrict__ mlpart,
    const float* __restrict__ Sc, float* __restrict__ out)
{
    const int g   = blockIdx.x;            // batch*128 + tile, 0..511
    const int tid = threadIdx.x;
    const int row = tid >> 3;              // 0..31
    const int seg = tid & 7;
    const int p0  = g * 2, p1 = g * 2 + 1;

    const float M0 = mlpart[(size_t)p0 * 64 + row];
    const float L0 = mlpart[(size_t)p0 * 64 + 32 + row];
    const float M1 = mlpart[(size_t)p1 * 64 + row];
    const float L1 = mlpart[(size_t)p1 * 64 + 32 + row];
    const float M  = fmaxf(M0, M1);
    const float f0 = EXP2(M0 - M);
    const float f1 = EXP2(M1 - M);
    const float invL = 1.f / (L0 * f0 + L1 * f1);

    const size_t grow = (size_t)g * 32 + row;
    const float* O0 = Opart + (size_t)p0 * 4096 + row * D;
    const float* O1 = Opart + (size_t)p1 * 4096 + row * D;
#pragma unroll
    for (int j = 0; j < 4; ++j) {
        const int c = (seg + j * 8) * 4;
        const float4 a0 = *(const float4*)(O0 + c);
        const float4 a1 = *(const float4*)(O1 + c);
        const float4 sc = *(const float4*)(Sc + grow * D + c);
        float4 o;
        o.x = (a0.x * f0 + a1.x * f1) * invL + sc.x;
        o.y = (a0.y * f0 + a1.y * f1) * invL + sc.y;
        o.z = (a0.z * f0 + a1.z * f1) * invL + sc.z;
        o.w = (a0.w * f0 + a1.w * f1) * invL + sc.w;
        *(float4*)(out + grow * D + c) = o;
    }
}

extern "C" void kernel_launch(void* const* d_in, const int* in_sizes, int n_in,
                              void* d_out, int out_size, void* d_ws, size_t ws_size,
                              hipStream_t stream) {
    const float* x  = (const float*)d_in[0];
    const float* Wk = (const float*)d_in[1];
    const float* bk = (const float*)d_in[2];
    const float* Wq = (const float*)d_in[3];
    const float* bq = (const float*)d_in[4];
    const float* Wv = (const float*)d_in[5];
    const float* bv = (const float*)d_in[6];
    const float* Ws = (const float*)d_in[7];
    const float* bs = (const float*)d_in[8];
    float* out = (float*)d_out;

    u16*   Kh = (u16*)d_ws;                       // 4 MB fp16 (log2e-scaled)
    u16*   Qh = Kh + (size_t)BN * D;              // 4 MB fp16
    u16*   Vt = Qh + (size_t)BN * D;              // 4 MB fp16, [b][c][m]
    float* Sc = (float*)(Vt + (size_t)BN * D);    // 8 MB fp32
    u16*   Wt = (u16*)(Sc + (size_t)BN * D);      // 256 KB fp16 W^T (4 mats)
    float* Opart  = (float*)(Wt + 4 * 32768);     // 16 MB fp32 partial O
    float* mlpart = Opart + (size_t)1024 * 4096;  // 256 KB fp32 (M, L)

    prep_kernel<<<128, 256, 0, stream>>>(Wk, Wq, Wv, Ws, Wt);
    proj_kernel<<<dim3(128, 4), 256, 0, stream>>>(x, Wt, bk, bq, bv, bs,
                                                  Kh, Qh, Vt, Sc);
    attn_kernel<<<1024, 256, 0, stream>>>(Kh, Qh, Vt, Opart, mlpart);
    merge_kernel<<<512, 256, 0, stream>>>(Opart, mlpart, Sc, out);
}

// Round 6
// 151.024 us; speedup vs baseline: 2.9337x; 1.2647x over previous
//
#include <hip/hip_runtime.h>
#include <math.h>

typedef unsigned short u16;
typedef __attribute__((ext_vector_type(8))) _Float16 half8;    // 8 fp16
typedef __attribute__((ext_vector_type(4))) float    f32x4;

#define BATCH 4
#define NPB   4096      // pixels per batch (H*W)
#define BN    16384     // BATCH * NPB
#define CC    256       // input channels
#define D     128       // output channels (C/2)
#define LOG2E 1.44269504088896f

#if __has_builtin(__builtin_amdgcn_exp2f)
#define EXP2(x) __builtin_amdgcn_exp2f(x)
#else
#define EXP2(x) exp2f(x)
#endif

// 16-lane (DPP row) reductions on the VALU pipe — no LDS crossbar.
template<int CTRL>
__device__ __forceinline__ float dpp_mov(float x) {
    return __builtin_bit_cast(float, __builtin_amdgcn_update_dpp(
        __builtin_bit_cast(int, x), __builtin_bit_cast(int, x),
        CTRL, 0xf, 0xf, false));
}
__device__ __forceinline__ float dpp_row_max(float x) {
    x = fmaxf(x, dpp_mov<0x128>(x));   // row_ror:8
    x = fmaxf(x, dpp_mov<0x124>(x));   // row_ror:4
    x = fmaxf(x, dpp_mov<0x122>(x));   // row_ror:2
    x = fmaxf(x, dpp_mov<0x121>(x));   // row_ror:1
    return x;
}
__device__ __forceinline__ float dpp_row_sum(float x) {
    x += dpp_mov<0x128>(x);
    x += dpp_mov<0x124>(x);
    x += dpp_mov<0x122>(x);
    x += dpp_mov<0x121>(x);
    return x;
}

// ---------------------------------------------------------------------------
// Prep: W[mat] (f32 [256][128]) -> Wt[mat][c][k] fp16 (c-major, contiguous k).
// mat 0 (K) pre-scaled by log2e. 128 blocks x 256 threads x 4 elements.
// ---------------------------------------------------------------------------
__global__ __launch_bounds__(256) void prep_kernel(
    const float* __restrict__ Wk, const float* __restrict__ Wq,
    const float* __restrict__ Wv, const float* __restrict__ Ws,
    u16* __restrict__ Wt)
{
    const int f   = (blockIdx.x * 256 + threadIdx.x) * 4;   // flat output idx
    const int mat = f >> 15;
    const int rem = f & 32767;
    const int c   = rem >> 8;
    const int k0  = rem & 255;
    const float* W = (mat == 0) ? Wk : (mat == 1) ? Wq : (mat == 2) ? Wv : Ws;
    const float scale = (mat == 0) ? LOG2E : 1.0f;
    _Float16 t4[4];
#pragma unroll
    for (int i = 0; i < 4; ++i)
        t4[i] = (_Float16)(W[(size_t)(k0 + i) * D + c] * scale);
    *(uint2*)&Wt[(size_t)mat * 32768 + (size_t)c * 256 + k0] = *(const uint2*)t4;
}

// ---------------------------------------------------------------------------
// Projection: grid (128, 4) = 128-pixel x-tile x one matrix per block.
// Same compute as the proven kernel; ONLY the Q (by=1) and V (by=2) store
// addresses change: they now emit MFMA-fragment-ordered layouts so attn can
// read each fragment as one contiguous, coalesced 1 KB global load.
//   Qf: element (m,k) at ((m>>4)*4 + (k>>5))*512 + ((k>>3)&3)*128 + (m&15)*8 + (k&7)
//   Vf (per batch): (c,m) at ((m>>5)*8 + (c>>4))*512 + (c&15)*32 + (m&31)
// ---------------------------------------------------------------------------
#define APJ 264         // As row pitch in u16 (528 B: 16B-aligned, 4-bank row shift)

__global__ __launch_bounds__(256, 2) void proj_kernel(
    const float* __restrict__ x, const u16* __restrict__ Wt,
    const float* __restrict__ bk, const float* __restrict__ bq,
    const float* __restrict__ bv, const float* __restrict__ bs,
    u16* __restrict__ Kh, u16* __restrict__ Qf,
    u16* __restrict__ Vf, float* __restrict__ Sc)
{
    __shared__ __align__(16) u16 As[128][APJ];   // 66 KB -> 2 blocks/CU

    const int tid = threadIdx.x;
    const int wv  = tid >> 6;
    const int l   = tid & 63;
    const int l15 = l & 15;
    const int l4  = l >> 4;
    const int by  = blockIdx.y;
    const int gm0 = blockIdx.x * 128;
    const int c0  = wv * 32;

    // ---- W fragments from Wt: wf[ct][kc], lane -> W[k=kc*32+l4*8..+8][c0+ct*16+l15]
    const u16* wb = Wt + (size_t)by * 32768 + (size_t)(c0 + l15) * 256 + l4 * 8;
    half8 wf[2][8];
#pragma unroll
    for (int ct = 0; ct < 2; ++ct)
#pragma unroll
        for (int kc = 0; kc < 8; ++kc)
            wf[ct][kc] = *(const half8*)(wb + ct * 16 * 256 + kc * 32);

    // ---- stage the 128x256 x-tile once (coalesced: thread t -> float4 i*256+t)
    {
        const float4* xg = (const float4*)(x + (size_t)gm0 * CC);
#pragma unroll 8
        for (int i = 0; i < 32; ++i) {
            const int f = i * 256 + tid;           // flat float4 index
            const float4 v = xg[f];
            const int row = f >> 6, col4 = f & 63;
            _Float16 h[4] = {(_Float16)v.x, (_Float16)v.y,
                             (_Float16)v.z, (_Float16)v.w};
            *(uint2*)&As[row][col4 * 4] = *(const uint2*)h;
        }
    }
    __syncthreads();

    f32x4 acc[8][2];
#pragma unroll
    for (int mt = 0; mt < 8; ++mt) {
        acc[mt][0] = (f32x4){0.f, 0.f, 0.f, 0.f};
        acc[mt][1] = (f32x4){0.f, 0.f, 0.f, 0.f};
    }

    if (by == 2) {
        for (int kc = 0; kc < 8; ++kc)
#pragma unroll
            for (int mt = 0; mt < 8; ++mt) {
                const half8 a = *(const half8*)&As[mt * 16 + l15][kc * 32 + l4 * 8];
                acc[mt][0] = __builtin_amdgcn_mfma_f32_16x16x32_f16(a, wf[0][kc], acc[mt][0], 0, 0, 0);
                acc[mt][1] = __builtin_amdgcn_mfma_f32_16x16x32_f16(a, wf[1][kc], acc[mt][1], 0, 0, 0);
            }
        // V: lane holds D[m = (gm0&4095)+l4*4+r + mt*16][c = c0+ct*16+l15].
        // Store into fragment layout Vf (per batch).
        const float bb[2] = {bv[c0 + l15], bv[c0 + 16 + l15]};
        const int batch = gm0 >> 12;
        const int mb    = (gm0 & 4095) >> 5;      // 32-m block base (local)
        u16* vbp = Vf + (size_t)batch * (D * NPB);
#pragma unroll
        for (int mt = 0; mt < 8; ++mt)
#pragma unroll
            for (int ct = 0; ct < 2; ++ct) {
                _Float16 t4[4];
#pragma unroll
                for (int r = 0; r < 4; ++r)
                    t4[r] = (_Float16)(acc[mt][ct][r] + bb[ct]);
                const int blk = (mb + (mt >> 1)) * 8 + wv * 2 + ct;
                const int off = blk * 512 + l15 * 32 + (mt & 1) * 16 + l4 * 4;
                *(uint2*)&vbp[off] = *(const uint2*)t4;
            }
    } else {
        for (int kc = 0; kc < 8; ++kc)
#pragma unroll
            for (int mt = 0; mt < 8; ++mt) {
                const half8 a = *(const half8*)&As[mt * 16 + l15][kc * 32 + l4 * 8];
                acc[mt][0] = __builtin_amdgcn_mfma_f32_16x16x32_f16(wf[0][kc], a, acc[mt][0], 0, 0, 0);
                acc[mt][1] = __builtin_amdgcn_mfma_f32_16x16x32_f16(wf[1][kc], a, acc[mt][1], 0, 0, 0);
            }
        // swapped: D[c][m] — lane holds c = c0+ct*16+l4*4+r, m = gm0+mt*16+l15
        if (by == 3) {
            float bb2[2][4];
#pragma unroll
            for (int ct = 0; ct < 2; ++ct)
#pragma unroll
                for (int r = 0; r < 4; ++r)
                    bb2[ct][r] = bs[c0 + ct * 16 + l4 * 4 + r];
#pragma unroll
            for (int mt = 0; mt < 8; ++mt) {
                const int m = gm0 + mt * 16 + l15;
#pragma unroll
                for (int ct = 0; ct < 2; ++ct) {
                    float4 v;
                    v.x = acc[mt][ct][0] + bb2[ct][0];
                    v.y = acc[mt][ct][1] + bb2[ct][1];
                    v.z = acc[mt][ct][2] + bb2[ct][2];
                    v.w = acc[mt][ct][3] + bb2[ct][3];
                    *(float4*)&Sc[(size_t)m * D + c0 + ct * 16 + l4 * 4] = v;
                }
            }
        } else if (by == 1) {
            // Q -> fragment layout Qf (indexed by GLOBAL m)
            float bb2[2][4];
#pragma unroll
            for (int ct = 0; ct < 2; ++ct)
#pragma unroll
                for (int r = 0; r < 4; ++r)
                    bb2[ct][r] = bq[c0 + ct * 16 + l4 * 4 + r];
#pragma unroll
            for (int mt = 0; mt < 8; ++mt) {
                const int blk = (((gm0 >> 4) + mt) << 2) + wv;
#pragma unroll
                for (int ct = 0; ct < 2; ++ct) {
                    _Float16 t4[4];
#pragma unroll
                    for (int r = 0; r < 4; ++r)
                        t4[r] = (_Float16)(acc[mt][ct][r] + bb2[ct][r]);
                    const int off = blk * 512 + (ct * 2 + (l4 >> 1)) * 128
                                    + l15 * 8 + (l4 & 1) * 4;
                    *(uint2*)&Qf[off] = *(const uint2*)t4;
                }
            }
        } else {
            // K -> row-major [m][c] (read once per block by attn), log2e-scaled
            float bb2[2][4];
#pragma unroll
            for (int ct = 0; ct < 2; ++ct)
#pragma unroll
                for (int r = 0; r < 4; ++r)
                    bb2[ct][r] = bk[c0 + ct * 16 + l4 * 4 + r] * LOG2E;
#pragma unroll
            for (int mt = 0; mt < 8; ++mt) {
                const int m = gm0 + mt * 16 + l15;
#pragma unroll
                for (int ct = 0; ct < 2; ++ct) {
                    _Float16 t4[4];
#pragma unroll
                    for (int r = 0; r < 4; ++r)
                        t4[r] = (_Float16)(acc[mt][ct][r] + bb2[ct][r]);
                    *(uint2*)&Kh[(size_t)m * D + c0 + ct * 16 + l4 * 4] =
                        *(const uint2*)t4;
                }
            }
        }
    }
}

// ---------------------------------------------------------------------------
// Flash attention v7: fragment-layout global reads -> registers; NO main-loop
// LDS staging, NO barriers, NO swizzle. 512 blocks x 32 n-rows; 4 waves = 4
// disjoint m-quarters (32 iters x 32 m), each computing all 32 n. Every MFMA /
// softmax / Ps path is byte-identical math to the proven v5 kernel — only the
// load addresses changed (Qf/Vf are pre-arranged so one wave-load = one
// contiguous 1 KB block, 100% L2-line efficiency). LDS: wave-private Ps
// transpose + one-time 4-slot merge.
// ---------------------------------------------------------------------------
#define VPP 40          // Ps row pitch (u16)
#define OBP 132         // Obuf row pitch (f32): 528 B, 16B-aligned

__global__ __launch_bounds__(256, 2) void attn_kernel(
    const u16* __restrict__ Kh, const u16* __restrict__ Qf,
    const u16* __restrict__ Vf, const float* __restrict__ Sc,
    float* __restrict__ out)
{
    __shared__ __align__(16) u16   Ps[4][2][16][VPP];   // 10 KB
    __shared__ __align__(16) float Obuf[4][32][OBP];    // 67.6 KB
    __shared__ float ml[4][2][32];                      // 1 KB

    const int tid = threadIdx.x;
    const int wv  = tid >> 6;          // m-quarter
    const int l   = tid & 63;
    const int l15 = l & 15;
    const int l4  = l >> 4;

    // XCD-affinity remap: each XCD pair serves one batch (K+Qf+Vf ~3 MB / L2)
    const int bx    = blockIdx.x;
    const int xcd   = bx & 7;
    const int batch = xcd >> 1;
    const int tile  = ((xcd & 1) << 6) | (bx >> 3);
    const int gr0   = batch * NPB + tile * 32;      // block's 32 K-rows (out rows)

    // ---- K A-frags (proven 16x16x32 mapping), held in registers all loop
    half8 kf[2][4];
#pragma unroll
    for (int nt = 0; nt < 2; ++nt)
#pragma unroll
        for (int kc = 0; kc < 4; ++kc)
            kf[nt][kc] = *(const half8*)(
                Kh + (size_t)(gr0 + nt * 16 + l15) * D + kc * 32 + l4 * 8);

    // ---- fragment-layout bases
    const int  qtb = (batch * NPB + wv * 1024) >> 4;   // Q 16-m tile base (global m)
    const int  vbb = wv * 32;                          // V 32-m block base (local m)
    const u16* vb  = Vf + (size_t)batch * (D * NPB);
    const int  vl  = l15 * 4 + l4;                     // V lane permutation

    f32x4 Oc[2][8];
#pragma unroll
    for (int nt = 0; nt < 2; ++nt)
#pragma unroll
        for (int ct = 0; ct < 8; ++ct)
            Oc[nt][ct] = (f32x4){0.f, 0.f, 0.f, 0.f};
    float mold[2][4], lsum[2][4];
#pragma unroll
    for (int nt = 0; nt < 2; ++nt)
#pragma unroll
        for (int r = 0; r < 4; ++r) { mold[nt][r] = -1e30f; lsum[nt][r] = 0.f; }

    for (int it = 0; it < 32; ++it) {
        // ---- all fragment loads up front (contiguous 1 KB per instruction)
        half8 qf[2][4];
#pragma unroll
        for (int mt = 0; mt < 2; ++mt)
#pragma unroll
            for (int kc = 0; kc < 4; ++kc)
                qf[mt][kc] = *(const half8*)(
                    Qf + (size_t)(((qtb + it * 2 + mt) << 2) + kc) * 512 + l * 8);
        half8 vf[8];
#pragma unroll
        for (int ct = 0; ct < 8; ++ct)
            vf[ct] = *(const half8*)(
                vb + (size_t)(((vbb + it) << 3) + ct) * 512 + vl * 8);

        // ---- S' = (K*log2e) @ Q^T : 32n x 32m, exp2 domain (proven path)
        f32x4 sacc[2][2];
        sacc[0][0] = (f32x4){0.f, 0.f, 0.f, 0.f};
        sacc[0][1] = (f32x4){0.f, 0.f, 0.f, 0.f};
        sacc[1][0] = (f32x4){0.f, 0.f, 0.f, 0.f};
        sacc[1][1] = (f32x4){0.f, 0.f, 0.f, 0.f};
        __builtin_amdgcn_s_setprio(1);
#pragma unroll
        for (int kc = 0; kc < 4; ++kc)
#pragma unroll
            for (int nt = 0; nt < 2; ++nt)
#pragma unroll
                for (int mt = 0; mt < 2; ++mt)
                    sacc[nt][mt] = __builtin_amdgcn_mfma_f32_16x16x32_f16(
                        kf[nt][kc], qf[mt][kc], sacc[nt][mt], 0, 0, 0);
        __builtin_amdgcn_s_setprio(0);

        // ---- online softmax (exp2 domain): DPP row-max over 16 m-lanes
#pragma unroll
        for (int nt = 0; nt < 2; ++nt)
#pragma unroll
            for (int r = 0; r < 4; ++r) {
                const float rmax  = dpp_row_max(fmaxf(sacc[nt][0][r], sacc[nt][1][r]));
                const float mnew  = fmaxf(mold[nt][r], rmax);
                const float alpha = EXP2(mold[nt][r] - mnew);
                mold[nt][r] = mnew;
                const float p0 = EXP2(sacc[nt][0][r] - mnew);
                const float p1 = EXP2(sacc[nt][1][r] - mnew);
                lsum[nt][r] = lsum[nt][r] * alpha + p0 + p1;
#pragma unroll
                for (int ct = 0; ct < 8; ++ct) Oc[nt][ct][r] *= alpha;
                Ps[wv][nt][l4 * 4 + r][l15]      = __builtin_bit_cast(u16, (_Float16)p0);
                Ps[wv][nt][l4 * 4 + r][16 + l15] = __builtin_bit_cast(u16, (_Float16)p1);
            }
        asm volatile("s_waitcnt lgkmcnt(0)" ::: "memory");   // wave-private Ps

        // ---- PV: O += P @ V (proven path)
        __builtin_amdgcn_s_setprio(1);
#pragma unroll
        for (int nt = 0; nt < 2; ++nt) {
            const half8 pf = *(const half8*)&Ps[wv][nt][l15][l4 * 8];
#pragma unroll
            for (int ct = 0; ct < 8; ++ct)
                Oc[nt][ct] = __builtin_amdgcn_mfma_f32_16x16x32_f16(
                    pf, vf[ct], Oc[nt][ct], 0, 0, 0);
        }
        __builtin_amdgcn_s_setprio(0);
    }

    // ---- full per-row sums across the 16 m-lanes (once, DPP)
#pragma unroll
    for (int nt = 0; nt < 2; ++nt)
#pragma unroll
        for (int r = 0; r < 4; ++r)
            lsum[nt][r] = dpp_row_sum(lsum[nt][r]);

    // ---- publish per-wave (m, l) per row
    if (l15 == 0) {
#pragma unroll
        for (int nt = 0; nt < 2; ++nt)
#pragma unroll
            for (int r = 0; r < 4; ++r) {
                ml[wv][0][nt * 16 + l4 * 4 + r] = mold[nt][r];
                ml[wv][1][nt * 16 + l4 * 4 + r] = lsum[nt][r];
            }
    }
    __syncthreads();

    // ---- write own partial into common max-frame slot
#pragma unroll
    for (int nt = 0; nt < 2; ++nt)
#pragma unroll
        for (int r = 0; r < 4; ++r) {
            const int row = nt * 16 + l4 * 4 + r;
            const float M = fmaxf(fmaxf(ml[0][0][row], ml[1][0][row]),
                                  fmaxf(ml[2][0][row], ml[3][0][row]));
            const float fw = EXP2(mold[nt][r] - M);
#pragma unroll
            for (int ct = 0; ct < 8; ++ct)
                Obuf[wv][row][ct * 16 + l15] = Oc[nt][ct][r] * fw;
        }
    __syncthreads();

    // ---- 4-slot merge: thread -> (row = wv*8 + l/8, 16 c per lane-octet)
    {
        const int row = wv * 8 + (l >> 3);
        const int cb  = (l & 7) * 16;
        const float M = fmaxf(fmaxf(ml[0][0][row], ml[1][0][row]),
                              fmaxf(ml[2][0][row], ml[3][0][row]));
        float L = 0.f;
#pragma unroll
        for (int s = 0; s < 4; ++s)
            L += ml[s][1][row] * EXP2(ml[s][0][row] - M);
        const float invL = 1.f / L;
        const size_t grow = (size_t)(gr0 + row);
#pragma unroll
        for (int j = 0; j < 4; ++j) {
            const int c = cb + j * 4;
            f32x4 a = *(const f32x4*)&Obuf[0][row][c];
#pragma unroll
            for (int s = 1; s < 4; ++s) {
                const f32x4 b2 = *(const f32x4*)&Obuf[s][row][c];
                a[0] += b2[0]; a[1] += b2[1]; a[2] += b2[2]; a[3] += b2[3];
            }
            const float4 sc = *(const float4*)&Sc[grow * D + c];
            float4 o;
            o.x = a[0] * invL + sc.x;
            o.y = a[1] * invL + sc.y;
            o.z = a[2] * invL + sc.z;
            o.w = a[3] * invL + sc.w;
            *(float4*)&out[grow * D + c] = o;
        }
    }
}

extern "C" void kernel_launch(void* const* d_in, const int* in_sizes, int n_in,
                              void* d_out, int out_size, void* d_ws, size_t ws_size,
                              hipStream_t stream) {
    const float* x  = (const float*)d_in[0];
    const float* Wk = (const float*)d_in[1];
    const float* bk = (const float*)d_in[2];
    const float* Wq = (const float*)d_in[3];
    const float* bq = (const float*)d_in[4];
    const float* Wv = (const float*)d_in[5];
    const float* bv = (const float*)d_in[6];
    const float* Ws = (const float*)d_in[7];
    const float* bs = (const float*)d_in[8];
    float* out = (float*)d_out;

    u16*   Kh = (u16*)d_ws;                       // 4 MB fp16 [m][c] (log2e-scaled)
    u16*   Qf = Kh + (size_t)BN * D;              // 4 MB fp16, fragment layout
    u16*   Vf = Qf + (size_t)BN * D;              // 4 MB fp16, fragment layout
    float* Sc = (float*)(Vf + (size_t)BN * D);    // 8 MB fp32
    u16*   Wt = (u16*)(Sc + (size_t)BN * D);      // 256 KB fp16 W^T (4 mats)

    prep_kernel<<<128, 256, 0, stream>>>(Wk, Wq, Wv, Ws, Wt);
    proj_kernel<<<dim3(128, 4), 256, 0, stream>>>(x, Wt, bk, bq, bv, bs,
                                                  Kh, Qf, Vf, Sc);
    attn_kernel<<<512, 256, 0, stream>>>(Kh, Qf, Vf, Sc, out);
}